// Round 12
// baseline (658.055 us; speedup 1.0000x reference)
//
#include <hip/hip_runtime.h>
#include <math.h>

static constexpr float kSceneScale = 4.0f;
static constexpr int   kGX    = 16;                  // bins in x
static constexpr int   kGY    = 32;                  // bins in y
static constexpr int   kGZ    = 32;                  // bins in z
static constexpr int   kNBin3 = kGX * kGY * kGZ;     // 16384 spatial bins
static constexpr int   kNBins = kNBin3 + 1;          // +1 = "outside"
static constexpr int   kNB    = 256;                 // histogram blocks
static constexpr unsigned kOutside = 0xFFFFFFFFu;    // inv[] sentinel

__device__ __forceinline__ void fma4(float4& acc, float w, const float4& c) {
    acc.x = fmaf(w, c.x, acc.x);
    acc.y = fmaf(w, c.y, acc.y);
    acc.z = fmaf(w, c.z, acc.z);
    acc.w = fmaf(w, c.w, acc.w);
}

template <int RES>
__device__ __forceinline__ void trilerp_acc(const float4* __restrict__ cb,
                                            float x, float y, float z,
                                            float4& acc) {
    const float s = (float)(RES - 1);
    float fx = x * s, fy = y * s, fz = z * s;
    int x0 = min((int)fx, RES - 2);
    int y0 = min((int)fy, RES - 2);
    int z0 = min((int)fz, RES - 2);
    float tx = fx - (float)x0;
    float ty = fy - (float)y0;
    float tz = fz - (float)z0;
    int base = (x0 * RES + y0) * RES + z0;
    float4 c000 = cb[base];
    float4 c001 = cb[base + 1];
    float4 c010 = cb[base + RES];
    float4 c011 = cb[base + RES + 1];
    float4 c100 = cb[base + RES * RES];
    float4 c101 = cb[base + RES * RES + 1];
    float4 c110 = cb[base + RES * RES + RES];
    float4 c111 = cb[base + RES * RES + RES + 1];
    float wx0 = 1.0f - tx, wx1 = tx;
    float wy0 = 1.0f - ty, wy1 = ty;
    float wz0 = 1.0f - tz, wz1 = tz;
    fma4(acc, wx0 * wy0 * wz0, c000);
    fma4(acc, wx0 * wy0 * wz1, c001);
    fma4(acc, wx0 * wy1 * wz0, c010);
    fma4(acc, wx0 * wy1 * wz1, c011);
    fma4(acc, wx1 * wy0 * wz0, c100);
    fma4(acc, wx1 * wy0 * wz1, c101);
    fma4(acc, wx1 * wy1 * wz0, c110);
    fma4(acc, wx1 * wy1 * wz1, c111);
}

__device__ __forceinline__ void load_p01(const float* __restrict__ pts, int i,
                                         float& x, float& y, float& z, bool& inside) {
    float px = pts[3 * i + 0] * (1.0f / kSceneScale);
    float py = pts[3 * i + 1] * (1.0f / kSceneScale);
    float pz = pts[3 * i + 2] * (1.0f / kSceneScale);
    inside = (fabsf(px) < 0.5f) && (fabsf(py) < 0.5f) && (fabsf(pz) < 0.5f);
    x = fminf(fmaxf(px + 0.5f, 0.0f), 1.0f);
    y = fminf(fmaxf(py + 0.5f, 0.0f), 1.0f);
    z = fminf(fmaxf(pz + 0.5f, 0.0f), 1.0f);
}

__device__ __forceinline__ unsigned key_from01(float x, float y, float z, bool inside) {
    if (!inside) return (unsigned)(kNBins - 1);
    int bx = min((int)(x * kGX), kGX - 1);
    int by = min((int)(y * kGY), kGY - 1);
    int bz = min((int)(z * kGZ), kGZ - 1);
    return (unsigned)((bx * kGY + by) * kGZ + bz);
}

// bijective XCD-contiguous swizzle (m204 form)
__device__ __forceinline__ int xcd_swz(int orig, int nwg) {
    const int NX = 8;
    int q = nwg / NX, r = nwg % NX;
    int xcd = orig % NX, j = orig / NX;
    int base = (xcd < r) ? xcd * (q + 1) : r * (q + 1) + (xcd - r) * q;
    return base + j;
}

// ---------- Pass A: per-block LDS histogram (dynamic LDS) ----------
__global__ __launch_bounds__(256) void keys_hist_kernel(
        const float* __restrict__ pts,
        unsigned* __restrict__ blockHist, int n, int chunk) {
    extern __shared__ unsigned hist[];
    int tid = threadIdx.x;
    for (int j = tid; j < kNBins; j += 256) hist[j] = 0;
    __syncthreads();
    int beg = blockIdx.x * chunk;
    int end = min(n, beg + chunk);
    for (int i = beg + tid; i < end; i += 256) {
        float x, y, z; bool inside;
        load_p01(pts, i, x, y, z, inside);
        atomicAdd(&hist[key_from01(x, y, z, inside)], 1u);
    }
    __syncthreads();
    for (int j = tid; j < kNBins; j += 256) blockHist[(size_t)j * kNB + blockIdx.x] = hist[j];
}

// ---------- Pass B1: scan 1024-element chunks ----------
__global__ __launch_bounds__(256) void scan_chunks_kernel(
        unsigned* __restrict__ data, unsigned* __restrict__ partials, int total) {
    __shared__ unsigned sums[256];
    int tid = threadIdx.x;
    int base = blockIdx.x * 1024 + tid * 4;
    uint4 v = make_uint4(0u, 0u, 0u, 0u);
    if (base + 3 < total) {
        v = *(const uint4*)(data + base);
    } else {
        unsigned* p = (unsigned*)&v;
        for (int k = 0; k < 4; ++k) if (base + k < total) p[k] = data[base + k];
    }
    unsigned s1 = v.x + v.y, s2 = s1 + v.z, s3 = s2 + v.w;
    sums[tid] = s3;
    __syncthreads();
    for (int off = 1; off < 256; off <<= 1) {
        unsigned t = (tid >= off) ? sums[tid - off] : 0u;
        __syncthreads();
        sums[tid] += t;
        __syncthreads();
    }
    unsigned excl = sums[tid] - s3;
    uint4 o;
    o.x = excl; o.y = excl + v.x; o.z = excl + s1; o.w = excl + s2;
    if (base + 3 < total) {
        *(uint4*)(data + base) = o;
    } else {
        unsigned* p = (unsigned*)&o;
        for (int k = 0; k < 4; ++k) if (base + k < total) data[base + k] = p[k];
    }
    if (tid == 255) partials[blockIdx.x] = sums[255];
}

// ---------- Pass B2: scan partials (1 block) ----------
__global__ __launch_bounds__(256) void scan_partials_kernel(unsigned* __restrict__ partials, int m) {
    __shared__ unsigned buf[256];
    __shared__ unsigned carry_s;
    int tid = threadIdx.x;
    if (tid == 0) carry_s = 0u;
    __syncthreads();
    for (int base = 0; base < m; base += 256) {
        unsigned v = (base + tid < m) ? partials[base + tid] : 0u;
        buf[tid] = v;
        __syncthreads();
        for (int off = 1; off < 256; off <<= 1) {
            unsigned t = (tid >= off) ? buf[tid - off] : 0u;
            __syncthreads();
            buf[tid] += t;
            __syncthreads();
        }
        unsigned incl = buf[tid];
        unsigned c = carry_s;
        if (base + tid < m) partials[base + tid] = c + incl - v;
        __syncthreads();
        if (tid == 255) carry_s = c + incl;
        __syncthreads();
    }
}

// ---------- Pass B3: add chunk offsets back ----------
__global__ __launch_bounds__(256) void scan_add_kernel(
        unsigned* __restrict__ data, const unsigned* __restrict__ partials, int total) {
    int tid = threadIdx.x;
    int base = blockIdx.x * 1024 + tid * 4;
    unsigned p = partials[blockIdx.x];
    if (base + 3 < total) {
        uint4 v = *(const uint4*)(data + base);
        v.x += p; v.y += p; v.z += p; v.w += p;
        *(uint4*)(data + base) = v;
    } else {
        for (int k = 0; k < 4; ++k) if (base + k < total) data[base + k] += p;
    }
}

// ---------- Pass C: scatter payloads + inverse permutation (dynamic LDS) ----------
__global__ __launch_bounds__(256) void scatter_kernel(
        const float* __restrict__ pts,
        const unsigned* __restrict__ blockHist,
        float4* __restrict__ spts, unsigned* __restrict__ inv,
        int n, int chunk) {
    extern __shared__ unsigned offs[];
    int tid = threadIdx.x;
    for (int j = tid; j < kNBins; j += 256) offs[j] = blockHist[(size_t)j * kNB + blockIdx.x];
    __syncthreads();
    int beg = blockIdx.x * chunk;
    int end = min(n, beg + chunk);
    for (int i = beg + tid; i < end; i += 256) {
        float x, y, z; bool inside;
        load_p01(pts, i, x, y, z, inside);
        unsigned k = key_from01(x, y, z, inside);
        unsigned pos = atomicAdd(&offs[k], 1u);
        if (inside) {
            spts[pos] = make_float4(x, y, z, 0.0f);
            inv[i] = pos;
        } else {
            inv[i] = kOutside;
        }
    }
}

// ---------- Pass D: sorted compute, ILP4, XCD-swizzled, coalesced writes ----------
__global__ __launch_bounds__(512) void compute_sorted_kernel(
        const float4* __restrict__ spts,
        const unsigned* __restrict__ nInsidePtr,
        const float4* __restrict__ cb0,
        const float4* __restrict__ cb1,
        const float4* __restrict__ cb2,
        const float4* __restrict__ cb3,
        const float4* __restrict__ cb4,
        float4* __restrict__ sout, int cgrid) {
    unsigned nIn = nInsidePtr[0];
    int bid = xcd_swz((int)blockIdx.x, cgrid);
    unsigned t0 = (unsigned)bid * 2048u + threadIdx.x;
    if (t0 >= nIn) return;
    unsigned t1 = t0 + 512u, t2 = t0 + 1024u, t3 = t0 + 1536u;
    bool v1 = t1 < nIn, v2 = t2 < nIn, v3 = t3 < nIn;

    float4 s0_ = spts[t0];
    float4 s1_ = v1 ? spts[t1] : s0_;
    float4 s2_ = v2 ? spts[t2] : s0_;
    float4 s3_ = v3 ? spts[t3] : s0_;

    float4 a0 = make_float4(0.f, 0.f, 0.f, 0.f);
    float4 a1 = make_float4(0.f, 0.f, 0.f, 0.f);
    float4 a2 = make_float4(0.f, 0.f, 0.f, 0.f);
    float4 a3 = make_float4(0.f, 0.f, 0.f, 0.f);

    trilerp_acc<16>(cb0, s0_.x, s0_.y, s0_.z, a0);
    trilerp_acc<16>(cb0, s1_.x, s1_.y, s1_.z, a1);
    trilerp_acc<16>(cb0, s2_.x, s2_.y, s2_.z, a2);
    trilerp_acc<16>(cb0, s3_.x, s3_.y, s3_.z, a3);

    trilerp_acc<32>(cb1, s0_.x, s0_.y, s0_.z, a0);
    trilerp_acc<32>(cb1, s1_.x, s1_.y, s1_.z, a1);
    trilerp_acc<32>(cb1, s2_.x, s2_.y, s2_.z, a2);
    trilerp_acc<32>(cb1, s3_.x, s3_.y, s3_.z, a3);

    trilerp_acc<64>(cb2, s0_.x, s0_.y, s0_.z, a0);
    trilerp_acc<64>(cb2, s1_.x, s1_.y, s1_.z, a1);
    trilerp_acc<64>(cb2, s2_.x, s2_.y, s2_.z, a2);
    trilerp_acc<64>(cb2, s3_.x, s3_.y, s3_.z, a3);

    trilerp_acc<128>(cb3, s0_.x, s0_.y, s0_.z, a0);
    trilerp_acc<128>(cb3, s1_.x, s1_.y, s1_.z, a1);
    trilerp_acc<128>(cb3, s2_.x, s2_.y, s2_.z, a2);
    trilerp_acc<128>(cb3, s3_.x, s3_.y, s3_.z, a3);

    trilerp_acc<256>(cb4, s0_.x, s0_.y, s0_.z, a0);
    trilerp_acc<256>(cb4, s1_.x, s1_.y, s1_.z, a1);
    trilerp_acc<256>(cb4, s2_.x, s2_.y, s2_.z, a2);
    trilerp_acc<256>(cb4, s3_.x, s3_.y, s3_.z, a3);

    sout[t0] = make_float4(a0.x, a0.y, a0.z, expf(a0.w));
    if (v1) sout[t1] = make_float4(a1.x, a1.y, a1.z, expf(a1.w));
    if (v2) sout[t2] = make_float4(a2.x, a2.y, a2.z, expf(a2.w));
    if (v3) sout[t3] = make_float4(a3.x, a3.y, a3.z, expf(a3.w));
}

// ---------- Pass E: unsort (coalesced out writes, gathered sout reads) ----------
__global__ __launch_bounds__(256) void unsort_kernel(
        const unsigned* __restrict__ inv,
        const float4* __restrict__ sout,
        float* __restrict__ out, int n) {
    int i = blockIdx.x * blockDim.x + threadIdx.x;
    if (i >= n) return;
    unsigned v = inv[i];
    float4 r = make_float4(0.0f, 0.0f, 0.0f, 0.0f);
    if (v != kOutside) r = sout[v];
    out[3 * i + 0] = r.x;
    out[3 * i + 1] = r.y;
    out[3 * i + 2] = r.z;
    out[(size_t)3 * n + i] = r.w;
}

// ---------- Fallback: direct kernel ----------
__global__ __launch_bounds__(256) void direct_kernel(
        const float* __restrict__ pts,
        const float4* __restrict__ cb0,
        const float4* __restrict__ cb1,
        const float4* __restrict__ cb2,
        const float4* __restrict__ cb3,
        const float4* __restrict__ cb4,
        float* __restrict__ out,
        int n) {
    int i = blockIdx.x * blockDim.x + threadIdx.x;
    if (i >= n) return;
    float x, y, z; bool inside;
    load_p01(pts, i, x, y, z, inside);
    float c0 = 0.0f, c1 = 0.0f, c2 = 0.0f, sg = 0.0f;
    if (inside) {
        float4 acc = make_float4(0.0f, 0.0f, 0.0f, 0.0f);
        trilerp_acc<16>(cb0, x, y, z, acc);
        trilerp_acc<32>(cb1, x, y, z, acc);
        trilerp_acc<64>(cb2, x, y, z, acc);
        trilerp_acc<128>(cb3, x, y, z, acc);
        trilerp_acc<256>(cb4, x, y, z, acc);
        c0 = acc.x; c1 = acc.y; c2 = acc.z; sg = expf(acc.w);
    }
    out[3 * i + 0] = c0;
    out[3 * i + 1] = c1;
    out[3 * i + 2] = c2;
    out[(size_t)3 * n + i] = sg;
}

extern "C" void kernel_launch(void* const* d_in, const int* in_sizes, int n_in,
                              void* d_out, int out_size, void* d_ws, size_t ws_size,
                              hipStream_t stream) {
    const float* pts = (const float*)d_in[0];
    const float4* cb0 = (const float4*)d_in[2];
    const float4* cb1 = (const float4*)d_in[3];
    const float4* cb2 = (const float4*)d_in[4];
    const float4* cb3 = (const float4*)d_in[5];
    const float4* cb4 = (const float4*)d_in[6];
    float* out = (float*)d_out;

    int n = in_sizes[0] / 3;

    const int histTotal = kNBins * kNB;                 // 16385*256
    const int nChunks   = (histTotal + 1023) / 1024;

    size_t off_spts = 0;
    size_t off_sout = off_spts + (size_t)n * 16;
    size_t off_hist = off_sout + (size_t)n * 16;
    size_t off_part = off_hist + (size_t)histTotal * 4;
    size_t off_inv  = off_part + (size_t)nChunks * 4;
    size_t need     = off_inv + (size_t)n * 4;

    dim3 block(256);
    int nwg = (n + 255) / 256;

    if (ws_size < need) {
        direct_kernel<<<dim3(nwg), block, 0, stream>>>(pts, cb0, cb1, cb2, cb3, cb4, out, n);
        return;
    }

    float4*   spts      = (float4*)((char*)d_ws + off_spts);
    float4*   sout      = (float4*)((char*)d_ws + off_sout);
    unsigned* blockHist = (unsigned*)((char*)d_ws + off_hist);
    unsigned* partials  = (unsigned*)((char*)d_ws + off_part);
    unsigned* inv       = (unsigned*)((char*)d_ws + off_inv);

    // nInside = exclusive-scan value at the start of the outside bin's row
    const unsigned* nInsidePtr = blockHist + (size_t)kNBin3 * kNB;

    int chunk = (n + kNB - 1) / kNB;
    int cgrid = (n + 2047) / 2048;
    size_t ldsBytes = (size_t)kNBins * sizeof(unsigned);   // 65540 B dynamic LDS

    keys_hist_kernel<<<dim3(kNB), block, ldsBytes, stream>>>(pts, blockHist, n, chunk);
    scan_chunks_kernel<<<dim3(nChunks), block, 0, stream>>>(blockHist, partials, histTotal);
    scan_partials_kernel<<<dim3(1), block, 0, stream>>>(partials, nChunks);
    scan_add_kernel<<<dim3(nChunks), block, 0, stream>>>(blockHist, partials, histTotal);
    scatter_kernel<<<dim3(kNB), block, ldsBytes, stream>>>(pts, blockHist, spts, inv, n, chunk);
    compute_sorted_kernel<<<dim3(cgrid), dim3(512), 0, stream>>>(
        spts, nInsidePtr, cb0, cb1, cb2, cb3, cb4, sout, cgrid);
    unsort_kernel<<<dim3(nwg), block, 0, stream>>>(inv, sout, out, n);
}

// Round 13
// 302.556 us; speedup vs baseline: 2.1750x; 2.1750x over previous
//
#include <hip/hip_runtime.h>
#include <math.h>

static constexpr float kSceneScale = 4.0f;
static constexpr int   kG     = 16;                 // sort grid per axis
static constexpr int   kNBin3 = kG * kG * kG;       // 4096 spatial bins
static constexpr int   kNBins = kNBin3 + 1;         // +1 = "outside"
static constexpr int   kNB    = 256;                // histogram blocks
static constexpr unsigned kOutside = 0xFFFFFFFFu;   // inv[] sentinel

__device__ __forceinline__ void fma4(float4& acc, float w, const float4& c) {
    acc.x = fmaf(w, c.x, acc.x);
    acc.y = fmaf(w, c.y, acc.y);
    acc.z = fmaf(w, c.z, acc.z);
    acc.w = fmaf(w, c.w, acc.w);
}

template <int RES>
__device__ __forceinline__ void trilerp_acc(const float4* __restrict__ cb,
                                            float x, float y, float z,
                                            float4& acc) {
    const float s = (float)(RES - 1);
    float fx = x * s, fy = y * s, fz = z * s;
    int x0 = min((int)fx, RES - 2);
    int y0 = min((int)fy, RES - 2);
    int z0 = min((int)fz, RES - 2);
    float tx = fx - (float)x0;
    float ty = fy - (float)y0;
    float tz = fz - (float)z0;
    int base = (x0 * RES + y0) * RES + z0;
    float4 c000 = cb[base];
    float4 c001 = cb[base + 1];
    float4 c010 = cb[base + RES];
    float4 c011 = cb[base + RES + 1];
    float4 c100 = cb[base + RES * RES];
    float4 c101 = cb[base + RES * RES + 1];
    float4 c110 = cb[base + RES * RES + RES];
    float4 c111 = cb[base + RES * RES + RES + 1];
    float wx0 = 1.0f - tx, wx1 = tx;
    float wy0 = 1.0f - ty, wy1 = ty;
    float wz0 = 1.0f - tz, wz1 = tz;
    fma4(acc, wx0 * wy0 * wz0, c000);
    fma4(acc, wx0 * wy0 * wz1, c001);
    fma4(acc, wx0 * wy1 * wz0, c010);
    fma4(acc, wx0 * wy1 * wz1, c011);
    fma4(acc, wx1 * wy0 * wz0, c100);
    fma4(acc, wx1 * wy0 * wz1, c101);
    fma4(acc, wx1 * wy1 * wz0, c110);
    fma4(acc, wx1 * wy1 * wz1, c111);
}

__device__ __forceinline__ void load_p01(const float* __restrict__ pts, int i,
                                         float& x, float& y, float& z, bool& inside) {
    float px = pts[3 * i + 0] * (1.0f / kSceneScale);
    float py = pts[3 * i + 1] * (1.0f / kSceneScale);
    float pz = pts[3 * i + 2] * (1.0f / kSceneScale);
    inside = (fabsf(px) < 0.5f) && (fabsf(py) < 0.5f) && (fabsf(pz) < 0.5f);
    x = fminf(fmaxf(px + 0.5f, 0.0f), 1.0f);
    y = fminf(fmaxf(py + 0.5f, 0.0f), 1.0f);
    z = fminf(fmaxf(pz + 0.5f, 0.0f), 1.0f);
}

__device__ __forceinline__ unsigned key_from01(float x, float y, float z, bool inside) {
    if (!inside) return (unsigned)(kNBins - 1);
    int bx = min((int)(x * kG), kG - 1);
    int by = min((int)(y * kG), kG - 1);
    int bz = min((int)(z * kG), kG - 1);
    return (unsigned)((bx * kG + by) * kG + bz);
}

// bijective XCD-contiguous swizzle (m204 form)
__device__ __forceinline__ int xcd_swz(int orig, int nwg) {
    const int NX = 8;
    int q = nwg / NX, r = nwg % NX;
    int xcd = orig % NX, j = orig / NX;
    int base = (xcd < r) ? xcd * (q + 1) : r * (q + 1) + (xcd - r) * q;
    return base + j;
}

// ---------- Pass A: per-block LDS histogram ----------
__global__ __launch_bounds__(256) void keys_hist_kernel(
        const float* __restrict__ pts,
        unsigned* __restrict__ blockHist, int n, int chunk) {
    __shared__ unsigned hist[kNBins];
    int tid = threadIdx.x;
    for (int j = tid; j < kNBins; j += 256) hist[j] = 0;
    __syncthreads();
    int beg = blockIdx.x * chunk;
    int end = min(n, beg + chunk);
    for (int i = beg + tid; i < end; i += 256) {
        float x, y, z; bool inside;
        load_p01(pts, i, x, y, z, inside);
        atomicAdd(&hist[key_from01(x, y, z, inside)], 1u);
    }
    __syncthreads();
    for (int j = tid; j < kNBins; j += 256) blockHist[(size_t)j * kNB + blockIdx.x] = hist[j];
}

// ---------- Pass B1: scan 1024-element chunks ----------
__global__ __launch_bounds__(256) void scan_chunks_kernel(
        unsigned* __restrict__ data, unsigned* __restrict__ partials, int total) {
    __shared__ unsigned sums[256];
    int tid = threadIdx.x;
    int base = blockIdx.x * 1024 + tid * 4;
    uint4 v = make_uint4(0u, 0u, 0u, 0u);
    if (base + 3 < total) {
        v = *(const uint4*)(data + base);
    } else {
        unsigned* p = (unsigned*)&v;
        for (int k = 0; k < 4; ++k) if (base + k < total) p[k] = data[base + k];
    }
    unsigned s1 = v.x + v.y, s2 = s1 + v.z, s3 = s2 + v.w;
    sums[tid] = s3;
    __syncthreads();
    for (int off = 1; off < 256; off <<= 1) {
        unsigned t = (tid >= off) ? sums[tid - off] : 0u;
        __syncthreads();
        sums[tid] += t;
        __syncthreads();
    }
    unsigned excl = sums[tid] - s3;
    uint4 o;
    o.x = excl; o.y = excl + v.x; o.z = excl + s1; o.w = excl + s2;
    if (base + 3 < total) {
        *(uint4*)(data + base) = o;
    } else {
        unsigned* p = (unsigned*)&o;
        for (int k = 0; k < 4; ++k) if (base + k < total) data[base + k] = p[k];
    }
    if (tid == 255) partials[blockIdx.x] = sums[255];
}

// ---------- Pass B2: scan partials (1 block) ----------
__global__ __launch_bounds__(256) void scan_partials_kernel(unsigned* __restrict__ partials, int m) {
    __shared__ unsigned buf[256];
    __shared__ unsigned carry_s;
    int tid = threadIdx.x;
    if (tid == 0) carry_s = 0u;
    __syncthreads();
    for (int base = 0; base < m; base += 256) {
        unsigned v = (base + tid < m) ? partials[base + tid] : 0u;
        buf[tid] = v;
        __syncthreads();
        for (int off = 1; off < 256; off <<= 1) {
            unsigned t = (tid >= off) ? buf[tid - off] : 0u;
            __syncthreads();
            buf[tid] += t;
            __syncthreads();
        }
        unsigned incl = buf[tid];
        unsigned c = carry_s;
        if (base + tid < m) partials[base + tid] = c + incl - v;
        __syncthreads();
        if (tid == 255) carry_s = c + incl;
        __syncthreads();
    }
}

// ---------- Pass B3: add chunk offsets back ----------
__global__ __launch_bounds__(256) void scan_add_kernel(
        unsigned* __restrict__ data, const unsigned* __restrict__ partials, int total) {
    int tid = threadIdx.x;
    int base = blockIdx.x * 1024 + tid * 4;
    unsigned p = partials[blockIdx.x];
    if (base + 3 < total) {
        uint4 v = *(const uint4*)(data + base);
        v.x += p; v.y += p; v.z += p; v.w += p;
        *(uint4*)(data + base) = v;
    } else {
        for (int k = 0; k < 4; ++k) if (base + k < total) data[base + k] += p;
    }
}

// ---------- Pass C: scatter payloads + inverse permutation ----------
__global__ __launch_bounds__(256) void scatter_kernel(
        const float* __restrict__ pts,
        const unsigned* __restrict__ blockHist,
        float4* __restrict__ spts, unsigned* __restrict__ inv,
        int n, int chunk) {
    __shared__ unsigned offs[kNBins];
    int tid = threadIdx.x;
    for (int j = tid; j < kNBins; j += 256) offs[j] = blockHist[(size_t)j * kNB + blockIdx.x];
    __syncthreads();
    int beg = blockIdx.x * chunk;
    int end = min(n, beg + chunk);
    for (int i = beg + tid; i < end; i += 256) {
        float x, y, z; bool inside;
        load_p01(pts, i, x, y, z, inside);
        unsigned k = key_from01(x, y, z, inside);
        unsigned pos = atomicAdd(&offs[k], 1u);
        if (inside) {
            spts[pos] = make_float4(x, y, z, 0.0f);
            inv[i] = pos;
        } else {
            inv[i] = kOutside;
        }
    }
}

// ---------- Pass D: sorted compute, ILP2, XCD-swizzled, coalesced writes ----------
__global__ __launch_bounds__(512) void compute_sorted_kernel(
        const float4* __restrict__ spts,
        const unsigned* __restrict__ nInsidePtr,
        const float4* __restrict__ cb0,
        const float4* __restrict__ cb1,
        const float4* __restrict__ cb2,
        const float4* __restrict__ cb3,
        const float4* __restrict__ cb4,
        float4* __restrict__ sout, int cgrid) {
    unsigned nIn = nInsidePtr[0];
    int bid = xcd_swz((int)blockIdx.x, cgrid);
    unsigned t0 = (unsigned)bid * 1024u + threadIdx.x;
    if (t0 >= nIn) return;
    unsigned t1 = t0 + 512u;
    bool doB = (t1 < nIn);

    float4 sA = spts[t0];
    float4 sB = doB ? spts[t1] : sA;

    float4 accA = make_float4(0.0f, 0.0f, 0.0f, 0.0f);
    float4 accB = make_float4(0.0f, 0.0f, 0.0f, 0.0f);

    trilerp_acc<16>(cb0, sA.x, sA.y, sA.z, accA);
    trilerp_acc<16>(cb0, sB.x, sB.y, sB.z, accB);
    trilerp_acc<32>(cb1, sA.x, sA.y, sA.z, accA);
    trilerp_acc<32>(cb1, sB.x, sB.y, sB.z, accB);
    trilerp_acc<64>(cb2, sA.x, sA.y, sA.z, accA);
    trilerp_acc<64>(cb2, sB.x, sB.y, sB.z, accB);
    trilerp_acc<128>(cb3, sA.x, sA.y, sA.z, accA);
    trilerp_acc<128>(cb3, sB.x, sB.y, sB.z, accB);
    trilerp_acc<256>(cb4, sA.x, sA.y, sA.z, accA);
    trilerp_acc<256>(cb4, sB.x, sB.y, sB.z, accB);

    sout[t0] = make_float4(accA.x, accA.y, accA.z, expf(accA.w));
    if (doB) sout[t1] = make_float4(accB.x, accB.y, accB.z, expf(accB.w));
}

// ---------- Pass E: unsort (coalesced out writes, gathered sout reads) ----------
__global__ __launch_bounds__(256) void unsort_kernel(
        const unsigned* __restrict__ inv,
        const float4* __restrict__ sout,
        float* __restrict__ out, int n) {
    int i = blockIdx.x * blockDim.x + threadIdx.x;
    if (i >= n) return;
    unsigned v = inv[i];
    float4 r = make_float4(0.0f, 0.0f, 0.0f, 0.0f);
    if (v != kOutside) r = sout[v];
    out[3 * i + 0] = r.x;
    out[3 * i + 1] = r.y;
    out[3 * i + 2] = r.z;
    out[(size_t)3 * n + i] = r.w;
}

// ---------- Fallback: direct kernel ----------
__global__ __launch_bounds__(256) void direct_kernel(
        const float* __restrict__ pts,
        const float4* __restrict__ cb0,
        const float4* __restrict__ cb1,
        const float4* __restrict__ cb2,
        const float4* __restrict__ cb3,
        const float4* __restrict__ cb4,
        float* __restrict__ out,
        int n) {
    int i = blockIdx.x * blockDim.x + threadIdx.x;
    if (i >= n) return;
    float x, y, z; bool inside;
    load_p01(pts, i, x, y, z, inside);
    float c0 = 0.0f, c1 = 0.0f, c2 = 0.0f, sg = 0.0f;
    if (inside) {
        float4 acc = make_float4(0.0f, 0.0f, 0.0f, 0.0f);
        trilerp_acc<16>(cb0, x, y, z, acc);
        trilerp_acc<32>(cb1, x, y, z, acc);
        trilerp_acc<64>(cb2, x, y, z, acc);
        trilerp_acc<128>(cb3, x, y, z, acc);
        trilerp_acc<256>(cb4, x, y, z, acc);
        c0 = acc.x; c1 = acc.y; c2 = acc.z; sg = expf(acc.w);
    }
    out[3 * i + 0] = c0;
    out[3 * i + 1] = c1;
    out[3 * i + 2] = c2;
    out[(size_t)3 * n + i] = sg;
}

extern "C" void kernel_launch(void* const* d_in, const int* in_sizes, int n_in,
                              void* d_out, int out_size, void* d_ws, size_t ws_size,
                              hipStream_t stream) {
    const float* pts = (const float*)d_in[0];
    const float4* cb0 = (const float4*)d_in[2];
    const float4* cb1 = (const float4*)d_in[3];
    const float4* cb2 = (const float4*)d_in[4];
    const float4* cb3 = (const float4*)d_in[5];
    const float4* cb4 = (const float4*)d_in[6];
    float* out = (float*)d_out;

    int n = in_sizes[0] / 3;

    const int histTotal = kNBins * kNB;                 // 4097*256 = 1,048,832
    const int nChunks   = (histTotal + 1023) / 1024;    // 1025

    size_t off_spts = 0;
    size_t off_sout = off_spts + (size_t)n * 16;
    size_t off_hist = off_sout + (size_t)n * 16;
    size_t off_part = off_hist + (size_t)histTotal * 4;
    size_t off_inv  = off_part + (size_t)nChunks * 4;
    size_t need     = off_inv + (size_t)n * 4;

    dim3 block(256);
    int nwg = (n + 255) / 256;

    if (ws_size < need) {
        direct_kernel<<<dim3(nwg), block, 0, stream>>>(pts, cb0, cb1, cb2, cb3, cb4, out, n);
        return;
    }

    float4*   spts      = (float4*)((char*)d_ws + off_spts);
    float4*   sout      = (float4*)((char*)d_ws + off_sout);
    unsigned* blockHist = (unsigned*)((char*)d_ws + off_hist);
    unsigned* partials  = (unsigned*)((char*)d_ws + off_part);
    unsigned* inv       = (unsigned*)((char*)d_ws + off_inv);

    // nInside = exclusive-scan value at the start of the outside bin's row
    const unsigned* nInsidePtr = blockHist + (size_t)kNBin3 * kNB;

    int chunk = (n + kNB - 1) / kNB;
    int cgrid = (n + 1023) / 1024;

    keys_hist_kernel<<<dim3(kNB), block, 0, stream>>>(pts, blockHist, n, chunk);
    scan_chunks_kernel<<<dim3(nChunks), block, 0, stream>>>(blockHist, partials, histTotal);
    scan_partials_kernel<<<dim3(1), block, 0, stream>>>(partials, nChunks);
    scan_add_kernel<<<dim3(nChunks), block, 0, stream>>>(blockHist, partials, histTotal);
    scatter_kernel<<<dim3(kNB), block, 0, stream>>>(pts, blockHist, spts, inv, n, chunk);
    compute_sorted_kernel<<<dim3(cgrid), dim3(512), 0, stream>>>(
        spts, nInsidePtr, cb0, cb1, cb2, cb3, cb4, sout, cgrid);
    unsort_kernel<<<dim3(nwg), block, 0, stream>>>(inv, sout, out, n);
}

// Round 14
// 287.304 us; speedup vs baseline: 2.2904x; 1.0531x over previous
//
#include <hip/hip_runtime.h>
#include <math.h>

static constexpr float kSceneScale = 4.0f;
static constexpr int   kG     = 16;                 // sort grid per axis
static constexpr int   kNBin3 = kG * kG * kG;       // 4096 spatial bins
static constexpr int   kNBins = kNBin3 + 1;         // +1 = "outside"
static constexpr int   kNB    = 256;                // histogram blocks
static constexpr unsigned kOutside = 0xFFFFFFFFu;   // inv[] sentinel

__device__ __forceinline__ void fma4(float4& acc, float w, const float4& c) {
    acc.x = fmaf(w, c.x, acc.x);
    acc.y = fmaf(w, c.y, acc.y);
    acc.z = fmaf(w, c.z, acc.z);
    acc.w = fmaf(w, c.w, acc.w);
}

template <int RES>
__device__ __forceinline__ void trilerp_acc(const float4* __restrict__ cb,
                                            float x, float y, float z,
                                            float4& acc) {
    const float s = (float)(RES - 1);
    float fx = x * s, fy = y * s, fz = z * s;
    int x0 = min((int)fx, RES - 2);
    int y0 = min((int)fy, RES - 2);
    int z0 = min((int)fz, RES - 2);
    float tx = fx - (float)x0;
    float ty = fy - (float)y0;
    float tz = fz - (float)z0;
    int base = (x0 * RES + y0) * RES + z0;
    float4 c000 = cb[base];
    float4 c001 = cb[base + 1];
    float4 c010 = cb[base + RES];
    float4 c011 = cb[base + RES + 1];
    float4 c100 = cb[base + RES * RES];
    float4 c101 = cb[base + RES * RES + 1];
    float4 c110 = cb[base + RES * RES + RES];
    float4 c111 = cb[base + RES * RES + RES + 1];
    float wx0 = 1.0f - tx, wx1 = tx;
    float wy0 = 1.0f - ty, wy1 = ty;
    float wz0 = 1.0f - tz, wz1 = tz;
    fma4(acc, wx0 * wy0 * wz0, c000);
    fma4(acc, wx0 * wy0 * wz1, c001);
    fma4(acc, wx0 * wy1 * wz0, c010);
    fma4(acc, wx0 * wy1 * wz1, c011);
    fma4(acc, wx1 * wy0 * wz0, c100);
    fma4(acc, wx1 * wy0 * wz1, c101);
    fma4(acc, wx1 * wy1 * wz0, c110);
    fma4(acc, wx1 * wy1 * wz1, c111);
}

__device__ __forceinline__ void load_p01(const float* __restrict__ pts, int i,
                                         float& x, float& y, float& z, bool& inside) {
    float px = pts[3 * i + 0] * (1.0f / kSceneScale);
    float py = pts[3 * i + 1] * (1.0f / kSceneScale);
    float pz = pts[3 * i + 2] * (1.0f / kSceneScale);
    inside = (fabsf(px) < 0.5f) && (fabsf(py) < 0.5f) && (fabsf(pz) < 0.5f);
    x = fminf(fmaxf(px + 0.5f, 0.0f), 1.0f);
    y = fminf(fmaxf(py + 0.5f, 0.0f), 1.0f);
    z = fminf(fmaxf(pz + 0.5f, 0.0f), 1.0f);
}

__device__ __forceinline__ unsigned key_from01(float x, float y, float z, bool inside) {
    if (!inside) return (unsigned)(kNBins - 1);
    int bx = min((int)(x * kG), kG - 1);
    int by = min((int)(y * kG), kG - 1);
    int bz = min((int)(z * kG), kG - 1);
    return (unsigned)((bx * kG + by) * kG + bz);
}

// ---------- Pass A: per-block LDS histogram ----------
__global__ __launch_bounds__(256) void keys_hist_kernel(
        const float* __restrict__ pts,
        unsigned* __restrict__ blockHist, int n, int chunk) {
    __shared__ unsigned hist[kNBins];
    int tid = threadIdx.x;
    for (int j = tid; j < kNBins; j += 256) hist[j] = 0;
    __syncthreads();
    int beg = blockIdx.x * chunk;
    int end = min(n, beg + chunk);
    for (int i = beg + tid; i < end; i += 256) {
        float x, y, z; bool inside;
        load_p01(pts, i, x, y, z, inside);
        atomicAdd(&hist[key_from01(x, y, z, inside)], 1u);
    }
    __syncthreads();
    for (int j = tid; j < kNBins; j += 256) blockHist[(size_t)j * kNB + blockIdx.x] = hist[j];
}

// ---------- Pass B1: scan 1024-element chunks ----------
__global__ __launch_bounds__(256) void scan_chunks_kernel(
        unsigned* __restrict__ data, unsigned* __restrict__ partials, int total) {
    __shared__ unsigned sums[256];
    int tid = threadIdx.x;
    int base = blockIdx.x * 1024 + tid * 4;
    uint4 v = make_uint4(0u, 0u, 0u, 0u);
    if (base + 3 < total) {
        v = *(const uint4*)(data + base);
    } else {
        unsigned* p = (unsigned*)&v;
        for (int k = 0; k < 4; ++k) if (base + k < total) p[k] = data[base + k];
    }
    unsigned s1 = v.x + v.y, s2 = s1 + v.z, s3 = s2 + v.w;
    sums[tid] = s3;
    __syncthreads();
    for (int off = 1; off < 256; off <<= 1) {
        unsigned t = (tid >= off) ? sums[tid - off] : 0u;
        __syncthreads();
        sums[tid] += t;
        __syncthreads();
    }
    unsigned excl = sums[tid] - s3;
    uint4 o;
    o.x = excl; o.y = excl + v.x; o.z = excl + s1; o.w = excl + s2;
    if (base + 3 < total) {
        *(uint4*)(data + base) = o;
    } else {
        unsigned* p = (unsigned*)&o;
        for (int k = 0; k < 4; ++k) if (base + k < total) data[base + k] = p[k];
    }
    if (tid == 255) partials[blockIdx.x] = sums[255];
}

// ---------- Pass B2: scan partials (1 block) ----------
__global__ __launch_bounds__(256) void scan_partials_kernel(unsigned* __restrict__ partials, int m) {
    __shared__ unsigned buf[256];
    __shared__ unsigned carry_s;
    int tid = threadIdx.x;
    if (tid == 0) carry_s = 0u;
    __syncthreads();
    for (int base = 0; base < m; base += 256) {
        unsigned v = (base + tid < m) ? partials[base + tid] : 0u;
        buf[tid] = v;
        __syncthreads();
        for (int off = 1; off < 256; off <<= 1) {
            unsigned t = (tid >= off) ? buf[tid - off] : 0u;
            __syncthreads();
            buf[tid] += t;
            __syncthreads();
        }
        unsigned incl = buf[tid];
        unsigned c = carry_s;
        if (base + tid < m) partials[base + tid] = c + incl - v;
        __syncthreads();
        if (tid == 255) carry_s = c + incl;
        __syncthreads();
    }
}

// ---------- Pass B3: add chunk offsets back ----------
__global__ __launch_bounds__(256) void scan_add_kernel(
        unsigned* __restrict__ data, const unsigned* __restrict__ partials, int total) {
    int tid = threadIdx.x;
    int base = blockIdx.x * 1024 + tid * 4;
    unsigned p = partials[blockIdx.x];
    if (base + 3 < total) {
        uint4 v = *(const uint4*)(data + base);
        v.x += p; v.y += p; v.z += p; v.w += p;
        *(uint4*)(data + base) = v;
    } else {
        for (int k = 0; k < 4; ++k) if (base + k < total) data[base + k] += p;
    }
}

// ---------- Pass C: scatter payloads + inverse permutation ----------
__global__ __launch_bounds__(256) void scatter_kernel(
        const float* __restrict__ pts,
        const unsigned* __restrict__ blockHist,
        float4* __restrict__ spts, unsigned* __restrict__ inv,
        int n, int chunk) {
    __shared__ unsigned offs[kNBins];
    int tid = threadIdx.x;
    for (int j = tid; j < kNBins; j += 256) offs[j] = blockHist[(size_t)j * kNB + blockIdx.x];
    __syncthreads();
    int beg = blockIdx.x * chunk;
    int end = min(n, beg + chunk);
    for (int i = beg + tid; i < end; i += 256) {
        float x, y, z; bool inside;
        load_p01(pts, i, x, y, z, inside);
        unsigned k = key_from01(x, y, z, inside);
        unsigned pos = atomicAdd(&offs[k], 1u);
        if (inside) {
            spts[pos] = make_float4(x, y, z, 0.0f);
            inv[i] = pos;
        } else {
            inv[i] = kOutside;
        }
    }
}

// ---------- Pass D: sorted compute, ILP2, long-latency LODs issued first ----------
__global__ __launch_bounds__(512) void compute_sorted_kernel(
        const float4* __restrict__ spts,
        const unsigned* __restrict__ nInsidePtr,
        const float4* __restrict__ cb0,
        const float4* __restrict__ cb1,
        const float4* __restrict__ cb2,
        const float4* __restrict__ cb3,
        const float4* __restrict__ cb4,
        float4* __restrict__ sout) {
    unsigned nIn = nInsidePtr[0];
    unsigned t0 = blockIdx.x * 1024u + threadIdx.x;
    if (t0 >= nIn) return;
    unsigned t1 = t0 + 512u;
    bool doB = (t1 < nIn);

    float4 sA = spts[t0];
    float4 sB = doB ? spts[t1] : sA;

    float4 accA = make_float4(0.0f, 0.0f, 0.0f, 0.0f);
    float4 accB = make_float4(0.0f, 0.0f, 0.0f, 0.0f);

    // HBM-miss-heavy LODs first so their latency overlaps the cached ones.
    trilerp_acc<256>(cb4, sA.x, sA.y, sA.z, accA);
    trilerp_acc<256>(cb4, sB.x, sB.y, sB.z, accB);
    trilerp_acc<128>(cb3, sA.x, sA.y, sA.z, accA);
    trilerp_acc<128>(cb3, sB.x, sB.y, sB.z, accB);
    trilerp_acc<64>(cb2, sA.x, sA.y, sA.z, accA);
    trilerp_acc<64>(cb2, sB.x, sB.y, sB.z, accB);
    trilerp_acc<32>(cb1, sA.x, sA.y, sA.z, accA);
    trilerp_acc<32>(cb1, sB.x, sB.y, sB.z, accB);
    trilerp_acc<16>(cb0, sA.x, sA.y, sA.z, accA);
    trilerp_acc<16>(cb0, sB.x, sB.y, sB.z, accB);

    sout[t0] = make_float4(accA.x, accA.y, accA.z, expf(accA.w));
    if (doB) sout[t1] = make_float4(accB.x, accB.y, accB.z, expf(accB.w));
}

// ---------- Pass E: unsort (coalesced out writes, gathered sout reads) ----------
__global__ __launch_bounds__(256) void unsort_kernel(
        const unsigned* __restrict__ inv,
        const float4* __restrict__ sout,
        float* __restrict__ out, int n) {
    int i = blockIdx.x * blockDim.x + threadIdx.x;
    if (i >= n) return;
    unsigned v = inv[i];
    float4 r = make_float4(0.0f, 0.0f, 0.0f, 0.0f);
    if (v != kOutside) r = sout[v];
    out[3 * i + 0] = r.x;
    out[3 * i + 1] = r.y;
    out[3 * i + 2] = r.z;
    out[(size_t)3 * n + i] = r.w;
}

// ---------- Fallback: direct kernel ----------
__global__ __launch_bounds__(256) void direct_kernel(
        const float* __restrict__ pts,
        const float4* __restrict__ cb0,
        const float4* __restrict__ cb1,
        const float4* __restrict__ cb2,
        const float4* __restrict__ cb3,
        const float4* __restrict__ cb4,
        float* __restrict__ out,
        int n) {
    int i = blockIdx.x * blockDim.x + threadIdx.x;
    if (i >= n) return;
    float x, y, z; bool inside;
    load_p01(pts, i, x, y, z, inside);
    float c0 = 0.0f, c1 = 0.0f, c2 = 0.0f, sg = 0.0f;
    if (inside) {
        float4 acc = make_float4(0.0f, 0.0f, 0.0f, 0.0f);
        trilerp_acc<16>(cb0, x, y, z, acc);
        trilerp_acc<32>(cb1, x, y, z, acc);
        trilerp_acc<64>(cb2, x, y, z, acc);
        trilerp_acc<128>(cb3, x, y, z, acc);
        trilerp_acc<256>(cb4, x, y, z, acc);
        c0 = acc.x; c1 = acc.y; c2 = acc.z; sg = expf(acc.w);
    }
    out[3 * i + 0] = c0;
    out[3 * i + 1] = c1;
    out[3 * i + 2] = c2;
    out[(size_t)3 * n + i] = sg;
}

extern "C" void kernel_launch(void* const* d_in, const int* in_sizes, int n_in,
                              void* d_out, int out_size, void* d_ws, size_t ws_size,
                              hipStream_t stream) {
    const float* pts = (const float*)d_in[0];
    const float4* cb0 = (const float4*)d_in[2];
    const float4* cb1 = (const float4*)d_in[3];
    const float4* cb2 = (const float4*)d_in[4];
    const float4* cb3 = (const float4*)d_in[5];
    const float4* cb4 = (const float4*)d_in[6];
    float* out = (float*)d_out;

    int n = in_sizes[0] / 3;

    const int histTotal = kNBins * kNB;                 // 4097*256 = 1,048,832
    const int nChunks   = (histTotal + 1023) / 1024;    // 1025

    size_t off_spts = 0;
    size_t off_sout = off_spts + (size_t)n * 16;
    size_t off_hist = off_sout + (size_t)n * 16;
    size_t off_part = off_hist + (size_t)histTotal * 4;
    size_t off_inv  = off_part + (size_t)nChunks * 4;
    size_t need     = off_inv + (size_t)n * 4;

    dim3 block(256);
    int nwg = (n + 255) / 256;

    if (ws_size < need) {
        direct_kernel<<<dim3(nwg), block, 0, stream>>>(pts, cb0, cb1, cb2, cb3, cb4, out, n);
        return;
    }

    float4*   spts      = (float4*)((char*)d_ws + off_spts);
    float4*   sout      = (float4*)((char*)d_ws + off_sout);
    unsigned* blockHist = (unsigned*)((char*)d_ws + off_hist);
    unsigned* partials  = (unsigned*)((char*)d_ws + off_part);
    unsigned* inv       = (unsigned*)((char*)d_ws + off_inv);

    // nInside = exclusive-scan value at the start of the outside bin's row
    const unsigned* nInsidePtr = blockHist + (size_t)kNBin3 * kNB;

    int chunk = (n + kNB - 1) / kNB;
    int cgrid = (n + 1023) / 1024;

    keys_hist_kernel<<<dim3(kNB), block, 0, stream>>>(pts, blockHist, n, chunk);
    scan_chunks_kernel<<<dim3(nChunks), block, 0, stream>>>(blockHist, partials, histTotal);
    scan_partials_kernel<<<dim3(1), block, 0, stream>>>(partials, nChunks);
    scan_add_kernel<<<dim3(nChunks), block, 0, stream>>>(blockHist, partials, histTotal);
    scatter_kernel<<<dim3(kNB), block, 0, stream>>>(pts, blockHist, spts, inv, n, chunk);
    compute_sorted_kernel<<<dim3(cgrid), dim3(512), 0, stream>>>(
        spts, nInsidePtr, cb0, cb1, cb2, cb3, cb4, sout);
    unsort_kernel<<<dim3(nwg), block, 0, stream>>>(inv, sout, out, n);
}

// Round 15
// 271.262 us; speedup vs baseline: 2.4259x; 1.0591x over previous
//
#include <hip/hip_runtime.h>
#include <math.h>

static constexpr float kSceneScale = 4.0f;
static constexpr int   kG     = 16;                 // sort grid per axis
static constexpr int   kNBin3 = kG * kG * kG;       // 4096 spatial bins
static constexpr int   kNBins = kNBin3 + 1;         // +1 = "outside"
static constexpr int   kNB    = 256;                // histogram blocks
static constexpr unsigned kOutside = 0xFFFFFFFFu;   // inv[] sentinel

__device__ __forceinline__ void fma4(float4& acc, float w, const float4& c) {
    acc.x = fmaf(w, c.x, acc.x);
    acc.y = fmaf(w, c.y, acc.y);
    acc.z = fmaf(w, c.z, acc.z);
    acc.w = fmaf(w, c.w, acc.w);
}

template <int RES>
__device__ __forceinline__ void trilerp_acc(const float4* __restrict__ cb,
                                            float x, float y, float z,
                                            float4& acc) {
    const float s = (float)(RES - 1);
    float fx = x * s, fy = y * s, fz = z * s;
    int x0 = min((int)fx, RES - 2);
    int y0 = min((int)fy, RES - 2);
    int z0 = min((int)fz, RES - 2);
    float tx = fx - (float)x0;
    float ty = fy - (float)y0;
    float tz = fz - (float)z0;
    int base = (x0 * RES + y0) * RES + z0;
    float4 c000 = cb[base];
    float4 c001 = cb[base + 1];
    float4 c010 = cb[base + RES];
    float4 c011 = cb[base + RES + 1];
    float4 c100 = cb[base + RES * RES];
    float4 c101 = cb[base + RES * RES + 1];
    float4 c110 = cb[base + RES * RES + RES];
    float4 c111 = cb[base + RES * RES + RES + 1];
    float wx0 = 1.0f - tx, wx1 = tx;
    float wy0 = 1.0f - ty, wy1 = ty;
    float wz0 = 1.0f - tz, wz1 = tz;
    fma4(acc, wx0 * wy0 * wz0, c000);
    fma4(acc, wx0 * wy0 * wz1, c001);
    fma4(acc, wx0 * wy1 * wz0, c010);
    fma4(acc, wx0 * wy1 * wz1, c011);
    fma4(acc, wx1 * wy0 * wz0, c100);
    fma4(acc, wx1 * wy0 * wz1, c101);
    fma4(acc, wx1 * wy1 * wz0, c110);
    fma4(acc, wx1 * wy1 * wz1, c111);
}

__device__ __forceinline__ void load_p01(const float* __restrict__ pts, int i,
                                         float& x, float& y, float& z, bool& inside) {
    float px = pts[3 * i + 0] * (1.0f / kSceneScale);
    float py = pts[3 * i + 1] * (1.0f / kSceneScale);
    float pz = pts[3 * i + 2] * (1.0f / kSceneScale);
    inside = (fabsf(px) < 0.5f) && (fabsf(py) < 0.5f) && (fabsf(pz) < 0.5f);
    x = fminf(fmaxf(px + 0.5f, 0.0f), 1.0f);
    y = fminf(fmaxf(py + 0.5f, 0.0f), 1.0f);
    z = fminf(fmaxf(pz + 0.5f, 0.0f), 1.0f);
}

__device__ __forceinline__ unsigned key_from01(float x, float y, float z, bool inside) {
    if (!inside) return (unsigned)(kNBins - 1);
    int bx = min((int)(x * kG), kG - 1);
    int by = min((int)(y * kG), kG - 1);
    int bz = min((int)(z * kG), kG - 1);
    return (unsigned)((bx * kG + by) * kG + bz);
}

// ---------- Pass A: per-block LDS histogram ----------
__global__ __launch_bounds__(256) void keys_hist_kernel(
        const float* __restrict__ pts,
        unsigned* __restrict__ blockHist, int n, int chunk) {
    __shared__ unsigned hist[kNBins];
    int tid = threadIdx.x;
    for (int j = tid; j < kNBins; j += 256) hist[j] = 0;
    __syncthreads();
    int beg = blockIdx.x * chunk;
    int end = min(n, beg + chunk);
    for (int i = beg + tid; i < end; i += 256) {
        float x, y, z; bool inside;
        load_p01(pts, i, x, y, z, inside);
        atomicAdd(&hist[key_from01(x, y, z, inside)], 1u);
    }
    __syncthreads();
    for (int j = tid; j < kNBins; j += 256) blockHist[(size_t)j * kNB + blockIdx.x] = hist[j];
}

// ---------- Pass B1: scan 1024-element chunks ----------
__global__ __launch_bounds__(256) void scan_chunks_kernel(
        unsigned* __restrict__ data, unsigned* __restrict__ partials, int total) {
    __shared__ unsigned sums[256];
    int tid = threadIdx.x;
    int base = blockIdx.x * 1024 + tid * 4;
    uint4 v = make_uint4(0u, 0u, 0u, 0u);
    if (base + 3 < total) {
        v = *(const uint4*)(data + base);
    } else {
        unsigned* p = (unsigned*)&v;
        for (int k = 0; k < 4; ++k) if (base + k < total) p[k] = data[base + k];
    }
    unsigned s1 = v.x + v.y, s2 = s1 + v.z, s3 = s2 + v.w;
    sums[tid] = s3;
    __syncthreads();
    for (int off = 1; off < 256; off <<= 1) {
        unsigned t = (tid >= off) ? sums[tid - off] : 0u;
        __syncthreads();
        sums[tid] += t;
        __syncthreads();
    }
    unsigned excl = sums[tid] - s3;
    uint4 o;
    o.x = excl; o.y = excl + v.x; o.z = excl + s1; o.w = excl + s2;
    if (base + 3 < total) {
        *(uint4*)(data + base) = o;
    } else {
        unsigned* p = (unsigned*)&o;
        for (int k = 0; k < 4; ++k) if (base + k < total) data[base + k] = p[k];
    }
    if (tid == 255) partials[blockIdx.x] = sums[255];
}

// ---------- Pass B2: scan partials (1 block) ----------
__global__ __launch_bounds__(256) void scan_partials_kernel(unsigned* __restrict__ partials, int m) {
    __shared__ unsigned buf[256];
    __shared__ unsigned carry_s;
    int tid = threadIdx.x;
    if (tid == 0) carry_s = 0u;
    __syncthreads();
    for (int base = 0; base < m; base += 256) {
        unsigned v = (base + tid < m) ? partials[base + tid] : 0u;
        buf[tid] = v;
        __syncthreads();
        for (int off = 1; off < 256; off <<= 1) {
            unsigned t = (tid >= off) ? buf[tid - off] : 0u;
            __syncthreads();
            buf[tid] += t;
            __syncthreads();
        }
        unsigned incl = buf[tid];
        unsigned c = carry_s;
        if (base + tid < m) partials[base + tid] = c + incl - v;
        __syncthreads();
        if (tid == 255) carry_s = c + incl;
        __syncthreads();
    }
}

// ---------- Pass B3: add chunk offsets back ----------
__global__ __launch_bounds__(256) void scan_add_kernel(
        unsigned* __restrict__ data, const unsigned* __restrict__ partials, int total) {
    int tid = threadIdx.x;
    int base = blockIdx.x * 1024 + tid * 4;
    unsigned p = partials[blockIdx.x];
    if (base + 3 < total) {
        uint4 v = *(const uint4*)(data + base);
        v.x += p; v.y += p; v.z += p; v.w += p;
        *(uint4*)(data + base) = v;
    } else {
        for (int k = 0; k < 4; ++k) if (base + k < total) data[base + k] += p;
    }
}

// ---------- Pass C: scatter payloads + inverse permutation ----------
__global__ __launch_bounds__(256) void scatter_kernel(
        const float* __restrict__ pts,
        const unsigned* __restrict__ blockHist,
        float4* __restrict__ spts, unsigned* __restrict__ inv,
        int n, int chunk) {
    __shared__ unsigned offs[kNBins];
    int tid = threadIdx.x;
    for (int j = tid; j < kNBins; j += 256) offs[j] = blockHist[(size_t)j * kNB + blockIdx.x];
    __syncthreads();
    int beg = blockIdx.x * chunk;
    int end = min(n, beg + chunk);
    for (int i = beg + tid; i < end; i += 256) {
        float x, y, z; bool inside;
        load_p01(pts, i, x, y, z, inside);
        unsigned k = key_from01(x, y, z, inside);
        unsigned pos = atomicAdd(&offs[k], 1u);
        if (inside) {
            spts[pos] = make_float4(x, y, z, 0.0f);
            inv[i] = pos;
        } else {
            inv[i] = kOutside;
        }
    }
}

// ---------- Pass D: sorted compute, ILP2, cheap-LODs-first (R10 order) ----------
__global__ __launch_bounds__(512) void compute_sorted_kernel(
        const float4* __restrict__ spts,
        const unsigned* __restrict__ nInsidePtr,
        const float4* __restrict__ cb0,
        const float4* __restrict__ cb1,
        const float4* __restrict__ cb2,
        const float4* __restrict__ cb3,
        const float4* __restrict__ cb4,
        float4* __restrict__ sout) {
    unsigned nIn = nInsidePtr[0];
    unsigned t0 = blockIdx.x * 1024u + threadIdx.x;
    if (t0 >= nIn) return;
    unsigned t1 = t0 + 512u;
    bool doB = (t1 < nIn);

    float4 sA = spts[t0];
    float4 sB = doB ? spts[t1] : sA;

    float4 accA = make_float4(0.0f, 0.0f, 0.0f, 0.0f);
    float4 accB = make_float4(0.0f, 0.0f, 0.0f, 0.0f);

    // Cheap cache-resident LODs first: their FMAs execute while cb3/cb4
    // HBM misses drain (cb4-first measured 213 µs vs this order's 196 µs).
    trilerp_acc<16>(cb0, sA.x, sA.y, sA.z, accA);
    trilerp_acc<16>(cb0, sB.x, sB.y, sB.z, accB);
    trilerp_acc<32>(cb1, sA.x, sA.y, sA.z, accA);
    trilerp_acc<32>(cb1, sB.x, sB.y, sB.z, accB);
    trilerp_acc<64>(cb2, sA.x, sA.y, sA.z, accA);
    trilerp_acc<64>(cb2, sB.x, sB.y, sB.z, accB);
    trilerp_acc<128>(cb3, sA.x, sA.y, sA.z, accA);
    trilerp_acc<128>(cb3, sB.x, sB.y, sB.z, accB);
    trilerp_acc<256>(cb4, sA.x, sA.y, sA.z, accA);
    trilerp_acc<256>(cb4, sB.x, sB.y, sB.z, accB);

    sout[t0] = make_float4(accA.x, accA.y, accA.z, expf(accA.w));
    if (doB) sout[t1] = make_float4(accB.x, accB.y, accB.z, expf(accB.w));
}

// ---------- Pass E: unsort (coalesced out writes, gathered sout reads) ----------
__global__ __launch_bounds__(256) void unsort_kernel(
        const unsigned* __restrict__ inv,
        const float4* __restrict__ sout,
        float* __restrict__ out, int n) {
    int i = blockIdx.x * blockDim.x + threadIdx.x;
    if (i >= n) return;
    unsigned v = inv[i];
    float4 r = make_float4(0.0f, 0.0f, 0.0f, 0.0f);
    if (v != kOutside) r = sout[v];
    out[3 * i + 0] = r.x;
    out[3 * i + 1] = r.y;
    out[3 * i + 2] = r.z;
    out[(size_t)3 * n + i] = r.w;
}

// ---------- Fallback: direct kernel ----------
__global__ __launch_bounds__(256) void direct_kernel(
        const float* __restrict__ pts,
        const float4* __restrict__ cb0,
        const float4* __restrict__ cb1,
        const float4* __restrict__ cb2,
        const float4* __restrict__ cb3,
        const float4* __restrict__ cb4,
        float* __restrict__ out,
        int n) {
    int i = blockIdx.x * blockDim.x + threadIdx.x;
    if (i >= n) return;
    float x, y, z; bool inside;
    load_p01(pts, i, x, y, z, inside);
    float c0 = 0.0f, c1 = 0.0f, c2 = 0.0f, sg = 0.0f;
    if (inside) {
        float4 acc = make_float4(0.0f, 0.0f, 0.0f, 0.0f);
        trilerp_acc<16>(cb0, x, y, z, acc);
        trilerp_acc<32>(cb1, x, y, z, acc);
        trilerp_acc<64>(cb2, x, y, z, acc);
        trilerp_acc<128>(cb3, x, y, z, acc);
        trilerp_acc<256>(cb4, x, y, z, acc);
        c0 = acc.x; c1 = acc.y; c2 = acc.z; sg = expf(acc.w);
    }
    out[3 * i + 0] = c0;
    out[3 * i + 1] = c1;
    out[3 * i + 2] = c2;
    out[(size_t)3 * n + i] = sg;
}

extern "C" void kernel_launch(void* const* d_in, const int* in_sizes, int n_in,
                              void* d_out, int out_size, void* d_ws, size_t ws_size,
                              hipStream_t stream) {
    const float* pts = (const float*)d_in[0];
    const float4* cb0 = (const float4*)d_in[2];
    const float4* cb1 = (const float4*)d_in[3];
    const float4* cb2 = (const float4*)d_in[4];
    const float4* cb3 = (const float4*)d_in[5];
    const float4* cb4 = (const float4*)d_in[6];
    float* out = (float*)d_out;

    int n = in_sizes[0] / 3;

    const int histTotal = kNBins * kNB;                 // 4097*256 = 1,048,832
    const int nChunks   = (histTotal + 1023) / 1024;    // 1025

    size_t off_spts = 0;
    size_t off_sout = off_spts + (size_t)n * 16;
    size_t off_hist = off_sout + (size_t)n * 16;
    size_t off_part = off_hist + (size_t)histTotal * 4;
    size_t off_inv  = off_part + (size_t)nChunks * 4;
    size_t need     = off_inv + (size_t)n * 4;

    dim3 block(256);
    int nwg = (n + 255) / 256;

    if (ws_size < need) {
        direct_kernel<<<dim3(nwg), block, 0, stream>>>(pts, cb0, cb1, cb2, cb3, cb4, out, n);
        return;
    }

    float4*   spts      = (float4*)((char*)d_ws + off_spts);
    float4*   sout      = (float4*)((char*)d_ws + off_sout);
    unsigned* blockHist = (unsigned*)((char*)d_ws + off_hist);
    unsigned* partials  = (unsigned*)((char*)d_ws + off_part);
    unsigned* inv       = (unsigned*)((char*)d_ws + off_inv);

    // nInside = exclusive-scan value at the start of the outside bin's row
    const unsigned* nInsidePtr = blockHist + (size_t)kNBin3 * kNB;

    int chunk = (n + kNB - 1) / kNB;
    int cgrid = (n + 1023) / 1024;

    keys_hist_kernel<<<dim3(kNB), block, 0, stream>>>(pts, blockHist, n, chunk);
    scan_chunks_kernel<<<dim3(nChunks), block, 0, stream>>>(blockHist, partials, histTotal);
    scan_partials_kernel<<<dim3(1), block, 0, stream>>>(partials, nChunks);
    scan_add_kernel<<<dim3(nChunks), block, 0, stream>>>(blockHist, partials, histTotal);
    scatter_kernel<<<dim3(kNB), block, 0, stream>>>(pts, blockHist, spts, inv, n, chunk);
    compute_sorted_kernel<<<dim3(cgrid), dim3(512), 0, stream>>>(
        spts, nInsidePtr, cb0, cb1, cb2, cb3, cb4, sout);
    unsort_kernel<<<dim3(nwg), block, 0, stream>>>(inv, sout, out, n);
}